// Round 12
// baseline (905.591 us; speedup 1.0000x reference)
//
#include <hip/hip_runtime.h>
#include <stdint.h>
#include <stddef.h>

// ---------------------------------------------------------------------------
// MinGRU NLP model forward on MI355X (gfx950).  ALL float I/O is fp32.
// Pipeline: embed -> [LN -> gates GEMM -> scan(+res)] x3 -> LN -> vocab GEMM.
// Gates GEMMs: proven m97 128x128 BK=32 2-phase structure (round-8 code).
// FINAL vocab GEMM: 256x256 tile, 8 waves (2x4), wave tile 128x64, BK=64,
// XOR-swizzled LDS (0 conflicts, round-10), 2-deep double buffer with
// counted vmcnt(8) (round-11 schedule: next tile's loads stay in flight
// across the whole compute phase; raw s_barrier, no drain in-loop).
// ROWFAST grid keeps B/A L3-resident (round-8: FETCH 1.77 -> 0.43 GB).
// Epilogue: C staged through LDS -> full 128B-line nt stores (round-6).
// Scan: 3-kernel chunked linear recurrence h = a*h + v (32 chunks x 64).
// ---------------------------------------------------------------------------

typedef __attribute__((ext_vector_type(4))) float f32x4;
typedef __attribute__((ext_vector_type(8))) short bf16x8;
typedef float f32x4u __attribute__((vector_size(16), aligned(4)));

__device__ __forceinline__ unsigned short f2bf(float f) {
  unsigned int u = __float_as_uint(f);
  u += 0x7FFFu + ((u >> 16) & 1u);  // RNE
  return (unsigned short)(u >> 16);
}

__device__ __forceinline__ void gload16(const void* g, void* l) {
  __builtin_amdgcn_global_load_lds(
      (const __attribute__((address_space(1))) void*)g,
      (__attribute__((address_space(3))) void*)l, 16, 0, 0);
}

#define MEMFENCE asm volatile("" ::: "memory")

// ---------------------------------------------------------------------------
// fp32 -> bf16 conversion, 8 elems/thread/iter, grid-stride.
__global__ __launch_bounds__(256) void cvt_kernel(
    const float* __restrict__ in, unsigned short* __restrict__ out, int n8) {
  int i = blockIdx.x * 256 + threadIdx.x;
  int stride = gridDim.x * 256;
  for (; i < n8; i += stride) {
    const float4* p = (const float4*)in + (size_t)i * 2;
    float4 a = p[0], b = p[1];
    bf16x8 o;
    o[0] = (short)f2bf(a.x); o[1] = (short)f2bf(a.y);
    o[2] = (short)f2bf(a.z); o[3] = (short)f2bf(a.w);
    o[4] = (short)f2bf(b.x); o[5] = (short)f2bf(b.y);
    o[6] = (short)f2bf(b.z); o[7] = (short)f2bf(b.w);
    *(bf16x8*)(out + (size_t)i * 8) = o;
  }
}

// ---------------------------------------------------------------------------
// Embedding gather + bf16 cast: x_bf[tok, 0:768] = bf16(embW[ids[tok], :])
__global__ __launch_bounds__(256) void embed_kernel(
    const int* __restrict__ ids, const float* __restrict__ embW,
    unsigned short* __restrict__ xbf) {
  int tok = blockIdx.x;
  int id = ids[tok];
  const float* src = embW + (size_t)id * 768;
  unsigned short* dst = xbf + (size_t)tok * 768;
  for (int j = threadIdx.x; j < 768; j += 256) dst[j] = f2bf(src[j]);
}

// ---------------------------------------------------------------------------
// LayerNorm over last dim D, one block per row. Output bf16.
template <int BF16IN, int D>
__global__ __launch_bounds__(256) void ln_kernel(
    const void* __restrict__ xin, const float* __restrict__ w,
    const float* __restrict__ b, unsigned short* __restrict__ xout,
    float eps) {
  constexpr int NV = D / 256;
  int row = blockIdx.x;
  int tid = threadIdx.x;
  int lane = tid & 63, wid = tid >> 6;
  const float* xf = (const float*)xin;
  const unsigned short* xb = (const unsigned short*)xin;
  float vals[NV];
  float s = 0.f, ss = 0.f;
#pragma unroll
  for (int i = 0; i < NV; i++) {
    size_t idx = (size_t)row * D + i * 256 + tid;
    float v;
    if (BF16IN) {
      unsigned int u = ((unsigned int)xb[idx]) << 16;
      v = __uint_as_float(u);
    } else {
      v = xf[idx];
    }
    vals[i] = v;
    s += v;
    ss += v * v;
  }
  for (int off = 32; off; off >>= 1) {
    s += __shfl_down(s, off);
    ss += __shfl_down(ss, off);
  }
  __shared__ float red[8];
  if (lane == 0) { red[wid] = s; red[4 + wid] = ss; }
  __syncthreads();
  s = red[0] + red[1] + red[2] + red[3];
  ss = red[4] + red[5] + red[6] + red[7];
  constexpr float invD = 1.f / (float)D;
  float mu = s * invD;
  float var = ss * invD - mu * mu;
  float inv = rsqrtf(var + eps);
#pragma unroll
  for (int i = 0; i < NV; i++) {
    int col = i * 256 + tid;
    size_t idx = (size_t)row * D + col;
    float y = (vals[i] - mu) * inv * w[col] + b[col];
    xout[idx] = f2bf(y);
  }
}

// ---------------------------------------------------------------------------
// 128x128 BK=32 2-phase GEMM (round-8 proven) for gates/res GEMMs.
// C[M,N] = A[M,K]*B[N,K]^T, fp32 out. Grid dim3(ncb, nrb), x fastest.
__global__ __launch_bounds__(256) void gemm_bt(
    const unsigned short* __restrict__ A, const unsigned short* __restrict__ B,
    float* __restrict__ C, int M, int N, int K) {
  __shared__ __align__(16) char smem[16896];
  unsigned short* lsA = (unsigned short*)smem;
  unsigned short* lsB = (unsigned short*)(smem + 8192);
  float* lsC = (float*)smem;

  const int tid = threadIdx.x;
  const int lane = tid & 63;
  const int wid = __builtin_amdgcn_readfirstlane(tid >> 6);
  const int row0 = blockIdx.y * 128;
  const int col0 = blockIdx.x * 128;

  const int srow = tid >> 2;
  const int skg = (tid & 3) * 8;

  const unsigned short* gA0 = A + (size_t)(row0 + srow) * K + skg;
  const unsigned short* gA1 = A + (size_t)(row0 + 64 + srow) * K + skg;
  const unsigned short* gB0 = B + (size_t)(col0 + srow) * K + skg;
  const unsigned short* gB1 = B + (size_t)(col0 + 64 + srow) * K + skg;

  char* ldsA0 = (char*)lsA + wid * 1024;
  char* ldsA1 = (char*)lsA + 4096 + wid * 1024;
  char* ldsB0 = (char*)lsB + wid * 1024;
  char* ldsB1 = (char*)lsB + 4096 + wid * 1024;

  const int wm = wid >> 1, wn = wid & 1;
  const unsigned short* pA = lsA + (wm * 64 + (lane & 15)) * 32 + (lane >> 4) * 8;
  const unsigned short* pB = lsB + (wn * 64 + (lane & 15)) * 32 + (lane >> 4) * 8;

  f32x4 acc[4][4] = {};

  for (int k0 = 0; k0 < K; k0 += 32) {
    gload16(gA0 + k0, ldsA0);
    gload16(gA1 + k0, ldsA1);
    gload16(gB0 + k0, ldsB0);
    gload16(gB1 + k0, ldsB1);
    __syncthreads();
    bf16x8 af[4], bfr[4];
#pragma unroll
    for (int i = 0; i < 4; i++) af[i] = *(const bf16x8*)(pA + i * 512);
#pragma unroll
    for (int i = 0; i < 4; i++) bfr[i] = *(const bf16x8*)(pB + i * 512);
#pragma unroll
    for (int i = 0; i < 4; i++)
#pragma unroll
      for (int j = 0; j < 4; j++)
        acc[i][j] = __builtin_amdgcn_mfma_f32_16x16x32_bf16(bfr[j], af[i],
                                                            acc[i][j], 0, 0, 0);
    __syncthreads();
  }

  const int mloc = lane & 15;
  const int ng = (lane >> 4) * 4;
  const int LDC = 132;
  const int trow = tid >> 5;
  const int tcol = (tid & 31) * 4;
#pragma unroll
  for (int c = 0; c < 4; c++) {
    if (wm == (c >> 1)) {
      const int i0 = 2 * (c & 1);
#pragma unroll
      for (int ii = 0; ii < 2; ii++)
#pragma unroll
        for (int j = 0; j < 4; j++)
          *(f32x4*)(lsC + (ii * 16 + mloc) * LDC + wn * 64 + j * 16 + ng) =
              acc[i0 + ii][j];
    }
    __syncthreads();
#pragma unroll
    for (int rr = 0; rr < 4; rr++) {
      const int r = rr * 8 + trow;
      const size_t gr = row0 + c * 32 + r;
      f32x4 v = *(const f32x4*)(lsC + r * LDC + tcol);
      *(f32x4*)(C + gr * N + col0 + tcol) = v;
    }
    __syncthreads();
  }
}

// ---------------------------------------------------------------------------
// FINAL vocab GEMM: 256x256 tile, 8 waves (2x4), wave tile 128x64, BK=64,
// XOR-swizzled LDS, 2-deep double buffer with counted vmcnt(8).
// C[M,N] = A[M,K]*B[N,K]^T + bias, fp32 nt full-line out.
// ROWFAST grid: blockIdx.x = row-block (fastest), blockIdx.y = col-block.
// LDS: 2 bufs x (A[256][64] + B[256][64]) bf16 = 128 KiB; epilogue unions.
__global__ __launch_bounds__(512) void gemm_final256(
    const unsigned short* __restrict__ A, const unsigned short* __restrict__ B,
    float* __restrict__ C, const float* __restrict__ bias, int M, int N,
    int K) {
  __shared__ __align__(16) char smem[131072];
  float* const lsC = (float*)smem;  // epilogue union (33792 B)

  const int t = threadIdx.x;
  const int l = t & 63;
  const int w = __builtin_amdgcn_readfirstlane(t >> 6);  // 0..7
  const int row0 = blockIdx.x * 256;
  const int col0 = blockIdx.y * 256;

  // Staging (round-9 refcheck'd addressing): per tile, per matrix: 4 issues
  // of 512 threads x 16B. Row = issue*64 + (t>>3), LDS granule t&7, global
  // granule (t&7)^(row&7) (pre-swizzled source; linear gload_lds dest).
  const int srow = t >> 3;                    // 0..63
  const int sg = ((t & 7) ^ (srow & 7)) * 8;  // pre-swizzled global elem off
  const unsigned short* aS0 = A + (size_t)(row0 + srow) * K + sg;
  const unsigned short* aS1 = A + (size_t)(row0 + 64 + srow) * K + sg;
  const unsigned short* aS2 = A + (size_t)(row0 + 128 + srow) * K + sg;
  const unsigned short* aS3 = A + (size_t)(row0 + 192 + srow) * K + sg;
  int b0 = min(col0 + srow, N - 1);
  int b1 = min(col0 + 64 + srow, N - 1);
  int b2 = min(col0 + 128 + srow, N - 1);
  int b3 = min(col0 + 192 + srow, N - 1);
  const unsigned short* bS0 = B + (size_t)b0 * K + sg;
  const unsigned short* bS1 = B + (size_t)b1 * K + sg;
  const unsigned short* bS2 = B + (size_t)b2 * K + sg;
  const unsigned short* bS3 = B + (size_t)b3 * K + sg;
  const int wOff = w * 1024;  // wave-uniform LDS chunk within an issue

  // Fragment reads: wave (wm,wn) owns rows wm*128..+128, cols wn*64..+64.
  const int wm = w >> 2, wn = w & 3;
  const int aRowB = (wm * 128 + (l & 15)) * 128;
  const int bRowB = (wn * 64 + (l & 15)) * 128;
  const int gk0 = ((l >> 4) ^ (l & 7)) * 16;        // ks=0 granule (swz)
  const int gk1 = ((4 + (l >> 4)) ^ (l & 7)) * 16;  // ks=1 granule (swz)

  f32x4 acc[8][4] = {};

#define STAGE(BUF, KOFF)                       \
  do {                                         \
    char* a_ = smem + (BUF) * 65536;           \
    char* b_ = a_ + 32768;                     \
    gload16(aS0 + (KOFF), a_ + wOff);          \
    gload16(aS1 + (KOFF), a_ + 8192 + wOff);   \
    gload16(aS2 + (KOFF), a_ + 16384 + wOff);  \
    gload16(aS3 + (KOFF), a_ + 24576 + wOff);  \
    gload16(bS0 + (KOFF), b_ + wOff);          \
    gload16(bS1 + (KOFF), b_ + 8192 + wOff);   \
    gload16(bS2 + (KOFF), b_ + 16384 + wOff);  \
    gload16(bS3 + (KOFF), b_ + 24576 + wOff);  \
  } while (0)

  // Prologue: stage tile 0 into buf 0.
  STAGE(0, 0);

  const int NK = K >> 6;
  for (int kt = 0; kt < NK; ++kt) {
    const int cur = kt & 1;
    const char* aB = smem + cur * 65536;
    const char* bB = aB + 32768;

    if (kt + 1 < NK) {
      STAGE(cur ^ 1, (kt + 1) << 6);  // buf^1 free: prev iter's trailing bar
      asm volatile("s_waitcnt vmcnt(8)" ::: "memory");  // tile kt landed
    } else {
      asm volatile("s_waitcnt vmcnt(0)" ::: "memory");
    }
    __builtin_amdgcn_s_barrier();
    MEMFENCE;

    bf16x8 bf[4][2];
#pragma unroll
    for (int j = 0; j < 4; j++) {
      bf[j][0] = *(const bf16x8*)(bB + bRowB + j * 2048 + gk0);
      bf[j][1] = *(const bf16x8*)(bB + bRowB + j * 2048 + gk1);
    }
    // Two A-halves of 4 fragment-rows each (keeps af live-range at 32 VGPR).
#pragma unroll
    for (int h = 0; h < 2; h++) {
      bf16x8 af[4][2];
#pragma unroll
      for (int i = 0; i < 4; i++) {
        af[i][0] = *(const bf16x8*)(aB + aRowB + (h * 4 + i) * 2048 + gk0);
        af[i][1] = *(const bf16x8*)(aB + aRowB + (h * 4 + i) * 2048 + gk1);
      }
#pragma unroll
      for (int i = 0; i < 4; i++)
#pragma unroll
        for (int j = 0; j < 4; j++) {
          acc[h * 4 + i][j] = __builtin_amdgcn_mfma_f32_16x16x32_bf16(
              bf[j][0], af[i][0], acc[h * 4 + i][j], 0, 0, 0);
          acc[h * 4 + i][j] = __builtin_amdgcn_mfma_f32_16x16x32_bf16(
              bf[j][1], af[i][1], acc[h * 4 + i][j], 0, 0, 0);
        }
    }

    MEMFENCE;
    __builtin_amdgcn_s_barrier();  // all reads of buf[cur] done before reuse
    MEMFENCE;
  }
#undef STAGE

  // ---- Epilogue: LDS transpose -> full-line nt streaming stores ----
  // 8 chunks of 32 rows x 256 cols (stride 264 f32). Chunk c rows
  // [32c,32c+32) are written by the 4 waves with wm == c>>2 (fr = 2(c&3)+ii).
  const int mloc = l & 15;
  const int ng = (l >> 4) * 4;
  const int LDC = 264;
#pragma unroll
  for (int c = 0; c < 8; c++) {
    if (wm == (c >> 2)) {
      const int fr0 = (c & 3) * 2;
#pragma unroll
      for (int ii = 0; ii < 2; ii++)
#pragma unroll
        for (int j = 0; j < 4; j++)
          *(f32x4*)(lsC + (ii * 16 + mloc) * LDC + wn * 64 + j * 16 + ng) =
              acc[fr0 + ii][j];
    }
    __syncthreads();
    // Stream 32x256 chunk: 512 threads, each row = 64 lanes x 16B = 1024B.
#pragma unroll
    for (int rr = 0; rr < 4; rr++) {
      const int r = rr * 8 + (t >> 6);
      const size_t gr = row0 + c * 32 + r;
      f32x4 v = *(const f32x4*)(lsC + r * LDC + (t & 63) * 4);
      const int n0 = col0 + (t & 63) * 4;
      if (col0 + 256 <= N) {
        const f32x4u bv = *(const f32x4u*)(bias + n0);
        f32x4u o;
#pragma unroll
        for (int q = 0; q < 4; q++) o[q] = v[q] + bv[q];
        __builtin_nontemporal_store(o, (f32x4u*)(C + gr * N + n0));
      } else {
#pragma unroll
        for (int q = 0; q < 4; q++)
          if (n0 + q < N) C[gr * N + n0 + q] = v[q] + bias[n0 + q];
      }
    }
    __syncthreads();
  }
}

// ---------------------------------------------------------------------------
// MinGRU scan, 3-kernel chunked linear recurrence.
__device__ __forceinline__ void gru_step(float gate, float hid, float& a,
                                         float& g) {
  a = 1.f / (1.f + expf(gate));  // sigmoid(-gate)
  g = (hid >= 0.f) ? (hid + 0.5f) : 1.f / (1.f + expf(-hid));
}

__global__ __launch_bounds__(256) void scan_compose(
    const float* __restrict__ gh, float* __restrict__ Acl,
    float* __restrict__ Vcl) {
  int ck = blockIdx.x;
  int hp = blockIdx.y * 256 + threadIdx.x;
  int b = hp >> 10, h = hp & 1023;
  const float* gb = gh + ((size_t)(b * 2048 + ck * 64)) * 2048 + h;
  float A = 1.f, V = 0.f;
  for (int t = 0; t < 64; t++) {
    float gate = gb[(size_t)t * 2048];
    float hid = gb[(size_t)t * 2048 + 1024];
    float a, g;
    gru_step(gate, hid, a, g);
    V = a * V + (1.f - a) * g;
    A *= a;
  }
  size_t i = (size_t)(b * 32 + ck) * 1024 + h;
  Acl[i] = A;
  Vcl[i] = V;
}

__global__ __launch_bounds__(256) void scan_prefix(
    const float* __restrict__ Acl, const float* __restrict__ Vcl,
    float* __restrict__ Hin) {
  int hp = blockIdx.x * 256 + threadIdx.x;
  int b = hp >> 10, h = hp & 1023;
  float hr = 0.5f;
  for (int ck = 0; ck < 32; ck++) {
    size_t i = (size_t)(b * 32 + ck) * 1024 + h;
    Hin[i] = hr;
    hr = Acl[i] * hr + Vcl[i];
  }
}

__global__ __launch_bounds__(256) void scan_emit(
    const float* __restrict__ gh, const float* __restrict__ Hin,
    const float* __restrict__ res, float* __restrict__ xout) {
  int ck = blockIdx.x;
  int hp = blockIdx.y * 256 + threadIdx.x;
  int b = hp >> 10, h = hp & 1023;
  const float* gb = gh + ((size_t)(b * 2048 + ck * 64)) * 2048 + h;
  const float* rb = res + ((size_t)(b * 2048 + ck * 64)) * 1024 + h;
  float* ob = xout + ((size_t)(b * 2048 + ck * 64)) * 1024 + h;
  float hc = Hin[(size_t)(b * 32 + ck) * 1024 + h];
  for (int t = 0; t < 64; t++) {
    float gate = gb[(size_t)t * 2048];
    float hid = gb[(size_t)t * 2048 + 1024];
    float a, g;
    gru_step(gate, hid, a, g);
    hc = a * hc + (1.f - a) * g;
    ob[(size_t)t * 1024] = hc + rb[(size_t)t * 1024];
  }
}

// ---------------------------------------------------------------------------
extern "C" void kernel_launch(void* const* d_in, const int* in_sizes, int n_in,
                              void* d_out, int out_size, void* d_ws,
                              size_t ws_size, hipStream_t stream) {
  (void)in_sizes; (void)n_in; (void)out_size; (void)ws_size;
  const int* ids = (const int*)d_in[0];
  const float* embW = (const float*)d_in[1];
  const float* ln0w = (const float*)d_in[2];
  const float* ln0b = (const float*)d_in[3];
  const float* g0W = (const float*)d_in[4];
  const float* ln1w = (const float*)d_in[5];
  const float* ln1b = (const float*)d_in[6];
  const float* g1W = (const float*)d_in[7];
  const float* ln2w = (const float*)d_in[8];
  const float* ln2b = (const float*)d_in[9];
  const float* g2W = (const float*)d_in[10];
  const float* r0W = (const float*)d_in[11];
  const float* lnfw = (const float*)d_in[12];
  const float* lnfb = (const float*)d_in[13];
  const float* fcW = (const float*)d_in[14];
  const float* fcb = (const float*)d_in[15];
  float* out = (float*)d_out;

  const int M = 4096;  // B*S
  const int V = 50257;

  // Workspace layout (~191.3 MB total).
  char* ws = (char*)d_ws;
  unsigned short* x_bf = (unsigned short*)(ws + 0);          //  6,291,456
  float* x_f = (float*)(ws + 6291456);                       // 16,777,216
  unsigned short* xn_bf = (unsigned short*)(ws + 23068672);  //  8,388,608
  float* gh = (float*)(ws + 31457280);                       // 33,554,432
  float* r0 = (float*)(ws + 65011712);                       // 16,777,216
  float* Acl = (float*)(ws + 81788928);                      //    262,144
  float* Vcl = (float*)(ws + 82051072);                      //    262,144
  float* Hin = (float*)(ws + 82313216);                      //    262,144
  unsigned short* gwbf = (unsigned short*)(ws + 82575360);   //  4,194,304
  unsigned short* rwbf = (unsigned short*)(ws + 86769664);   //  1,572,864
  unsigned short* fcwbf = (unsigned short*)(ws + 88342528);  // 102,926,336

  auto cvt = [&](const float* src, unsigned short* dst, int n) {
    int n8 = n / 8;
    int grid = min((n8 + 255) / 256, 2048);
    cvt_kernel<<<grid, 256, 0, stream>>>(src, dst, n8);
  };

  embed_kernel<<<M, 256, 0, stream>>>(ids, embW, x_bf);
  cvt(fcW, fcwbf, V * 1024);
  cvt(r0W, rwbf, 1024 * 768);

  // ---- layer 0 (in 768 -> out 1024, residual = x @ res0_W^T) ----
  cvt(g0W, gwbf, 2048 * 768);
  ln_kernel<1, 768><<<M, 256, 0, stream>>>(x_bf, ln0w, ln0b, xn_bf, 1e-5f);
  gemm_bt<<<dim3(16, 32), 256, 0, stream>>>(xn_bf, gwbf, gh, M, 2048, 768);
  gemm_bt<<<dim3(8, 32), 256, 0, stream>>>(x_bf, rwbf, r0, M, 1024, 768);
  scan_compose<<<dim3(32, 8), 256, 0, stream>>>(gh, Acl, Vcl);
  scan_prefix<<<8, 256, 0, stream>>>(Acl, Vcl, Hin);
  scan_emit<<<dim3(32, 8), 256, 0, stream>>>(gh, Hin, r0, x_f);

  // ---- layer 1 (identity residual) ----
  cvt(g1W, gwbf, 2048 * 1024);
  ln_kernel<0, 1024><<<M, 256, 0, stream>>>(x_f, ln1w, ln1b, xn_bf, 1e-5f);
  gemm_bt<<<dim3(16, 32), 256, 0, stream>>>(xn_bf, gwbf, gh, M, 2048, 1024);
  scan_compose<<<dim3(32, 8), 256, 0, stream>>>(gh, Acl, Vcl);
  scan_prefix<<<8, 256, 0, stream>>>(Acl, Vcl, Hin);
  scan_emit<<<dim3(32, 8), 256, 0, stream>>>(gh, Hin, x_f, x_f);

  // ---- layer 2 (identity residual) ----
  cvt(g2W, gwbf, 2048 * 1024);
  ln_kernel<0, 1024><<<M, 256, 0, stream>>>(x_f, ln2w, ln2b, xn_bf, 1e-5f);
  gemm_bt<<<dim3(16, 32), 256, 0, stream>>>(xn_bf, gwbf, gh, M, 2048, 1024);
  scan_compose<<<dim3(32, 8), 256, 0, stream>>>(gh, Acl, Vcl);
  scan_prefix<<<8, 256, 0, stream>>>(Acl, Vcl, Hin);
  scan_emit<<<dim3(32, 8), 256, 0, stream>>>(gh, Hin, x_f, x_f);

  // ---- final LN (eps=0) + vocab GEMM (256^2, dbuf+vmcnt(8)), fp32 out ----
  // ROWFAST grid: x = 16 row-blocks (fastest), y = 197 col-blocks.
  ln_kernel<0, 1024><<<M, 256, 0, stream>>>(x_f, lnfw, lnfb, xn_bf, 0.0f);
  gemm_final256<<<dim3(16, (V + 255) / 256), 512, 0, stream>>>(
      xn_bf, fcwbf, out, fcb, M, V, 1024);
}

// Round 13
// 887.571 us; speedup vs baseline: 1.0203x; 1.0203x over previous
//
#include <hip/hip_runtime.h>
#include <stdint.h>
#include <stddef.h>

// ---------------------------------------------------------------------------
// MinGRU NLP model forward on MI355X (gfx950).  ALL float I/O is fp32.
// Pipeline: embed -> [LN -> gates GEMM -> scan(+res)] x3 -> LN -> vocab GEMM.
// Gates GEMMs: m97 128x128 BK=32 2-phase structure, bf16 OUTPUT (halves the
// gh/r0 write + scan read traffic; scan converts back to fp32 on load).
// FINAL vocab GEMM: 256x256 tile, 8 waves, BK=64, XOR-swizzled LDS,
// 2-deep double buffer with counted vmcnt(8) (round-12 proven).
// ROWFAST grid keeps B/A L3-resident. Epilogue: LDS -> full-line stores
// (LDC=260: 2-way bank aliasing = free).
// Scan: 3-kernel chunked linear recurrence h = a*h + v (32 chunks x 64);
// gh/r0 in bf16, h-state and activations x_f in fp32.
// ---------------------------------------------------------------------------

typedef __attribute__((ext_vector_type(4))) float f32x4;
typedef __attribute__((ext_vector_type(8))) short bf16x8;
typedef __attribute__((ext_vector_type(4))) unsigned short u16x4;
typedef float f32x4u __attribute__((vector_size(16), aligned(4)));

__device__ __forceinline__ unsigned short f2bf(float f) {
  unsigned int u = __float_as_uint(f);
  u += 0x7FFFu + ((u >> 16) & 1u);  // RNE
  return (unsigned short)(u >> 16);
}
__device__ __forceinline__ float bf2f(unsigned short u) {
  return __uint_as_float(((unsigned int)u) << 16);
}

__device__ __forceinline__ void gload16(const void* g, void* l) {
  __builtin_amdgcn_global_load_lds(
      (const __attribute__((address_space(1))) void*)g,
      (__attribute__((address_space(3))) void*)l, 16, 0, 0);
}

#define MEMFENCE asm volatile("" ::: "memory")

// ---------------------------------------------------------------------------
// fp32 -> bf16 conversion, 8 elems/thread/iter, grid-stride.
__global__ __launch_bounds__(256) void cvt_kernel(
    const float* __restrict__ in, unsigned short* __restrict__ out, int n8) {
  int i = blockIdx.x * 256 + threadIdx.x;
  int stride = gridDim.x * 256;
  for (; i < n8; i += stride) {
    const float4* p = (const float4*)in + (size_t)i * 2;
    float4 a = p[0], b = p[1];
    bf16x8 o;
    o[0] = (short)f2bf(a.x); o[1] = (short)f2bf(a.y);
    o[2] = (short)f2bf(a.z); o[3] = (short)f2bf(a.w);
    o[4] = (short)f2bf(b.x); o[5] = (short)f2bf(b.y);
    o[6] = (short)f2bf(b.z); o[7] = (short)f2bf(b.w);
    *(bf16x8*)(out + (size_t)i * 8) = o;
  }
}

// ---------------------------------------------------------------------------
// Embedding gather + bf16 cast: x_bf[tok, 0:768] = bf16(embW[ids[tok], :])
__global__ __launch_bounds__(256) void embed_kernel(
    const int* __restrict__ ids, const float* __restrict__ embW,
    unsigned short* __restrict__ xbf) {
  int tok = blockIdx.x;
  int id = ids[tok];
  const float* src = embW + (size_t)id * 768;
  unsigned short* dst = xbf + (size_t)tok * 768;
  for (int j = threadIdx.x; j < 768; j += 256) dst[j] = f2bf(src[j]);
}

// ---------------------------------------------------------------------------
// LayerNorm over last dim D, one block per row. Output bf16.
template <int BF16IN, int D>
__global__ __launch_bounds__(256) void ln_kernel(
    const void* __restrict__ xin, const float* __restrict__ w,
    const float* __restrict__ b, unsigned short* __restrict__ xout,
    float eps) {
  constexpr int NV = D / 256;
  int row = blockIdx.x;
  int tid = threadIdx.x;
  int lane = tid & 63, wid = tid >> 6;
  const float* xf = (const float*)xin;
  const unsigned short* xb = (const unsigned short*)xin;
  float vals[NV];
  float s = 0.f, ss = 0.f;
#pragma unroll
  for (int i = 0; i < NV; i++) {
    size_t idx = (size_t)row * D + i * 256 + tid;
    float v = BF16IN ? bf2f(xb[idx]) : xf[idx];
    vals[i] = v;
    s += v;
    ss += v * v;
  }
  for (int off = 32; off; off >>= 1) {
    s += __shfl_down(s, off);
    ss += __shfl_down(ss, off);
  }
  __shared__ float red[8];
  if (lane == 0) { red[wid] = s; red[4 + wid] = ss; }
  __syncthreads();
  s = red[0] + red[1] + red[2] + red[3];
  ss = red[4] + red[5] + red[6] + red[7];
  constexpr float invD = 1.f / (float)D;
  float mu = s * invD;
  float var = ss * invD - mu * mu;
  float inv = rsqrtf(var + eps);
#pragma unroll
  for (int i = 0; i < NV; i++) {
    int col = i * 256 + tid;
    size_t idx = (size_t)row * D + col;
    float y = (vals[i] - mu) * inv * w[col] + b[col];
    xout[idx] = f2bf(y);
  }
}

// ---------------------------------------------------------------------------
// 128x128 BK=32 2-phase GEMM for gates/res GEMMs. BF16OUT=1: write bf16
// (full-line: each streamed row is 256B). Grid dim3(ncb, nrb), x fastest.
template <int BF16OUT>
__global__ __launch_bounds__(256) void gemm_bt(
    const unsigned short* __restrict__ A, const unsigned short* __restrict__ B,
    void* __restrict__ Cout, int M, int N, int K) {
  __shared__ __align__(16) char smem[16896];
  unsigned short* lsA = (unsigned short*)smem;
  unsigned short* lsB = (unsigned short*)(smem + 8192);
  float* lsC = (float*)smem;

  const int tid = threadIdx.x;
  const int lane = tid & 63;
  const int wid = __builtin_amdgcn_readfirstlane(tid >> 6);
  const int row0 = blockIdx.y * 128;
  const int col0 = blockIdx.x * 128;

  const int srow = tid >> 2;
  const int skg = (tid & 3) * 8;

  const unsigned short* gA0 = A + (size_t)(row0 + srow) * K + skg;
  const unsigned short* gA1 = A + (size_t)(row0 + 64 + srow) * K + skg;
  const unsigned short* gB0 = B + (size_t)(col0 + srow) * K + skg;
  const unsigned short* gB1 = B + (size_t)(col0 + 64 + srow) * K + skg;

  char* ldsA0 = (char*)lsA + wid * 1024;
  char* ldsA1 = (char*)lsA + 4096 + wid * 1024;
  char* ldsB0 = (char*)lsB + wid * 1024;
  char* ldsB1 = (char*)lsB + 4096 + wid * 1024;

  const int wm = wid >> 1, wn = wid & 1;
  const unsigned short* pA = lsA + (wm * 64 + (lane & 15)) * 32 + (lane >> 4) * 8;
  const unsigned short* pB = lsB + (wn * 64 + (lane & 15)) * 32 + (lane >> 4) * 8;

  f32x4 acc[4][4] = {};

  for (int k0 = 0; k0 < K; k0 += 32) {
    gload16(gA0 + k0, ldsA0);
    gload16(gA1 + k0, ldsA1);
    gload16(gB0 + k0, ldsB0);
    gload16(gB1 + k0, ldsB1);
    __syncthreads();
    bf16x8 af[4], bfr[4];
#pragma unroll
    for (int i = 0; i < 4; i++) af[i] = *(const bf16x8*)(pA + i * 512);
#pragma unroll
    for (int i = 0; i < 4; i++) bfr[i] = *(const bf16x8*)(pB + i * 512);
#pragma unroll
    for (int i = 0; i < 4; i++)
#pragma unroll
      for (int j = 0; j < 4; j++)
        acc[i][j] = __builtin_amdgcn_mfma_f32_16x16x32_bf16(bfr[j], af[i],
                                                            acc[i][j], 0, 0, 0);
    __syncthreads();
  }

  const int mloc = lane & 15;
  const int ng = (lane >> 4) * 4;
  const int LDC = 132;
  const int trow = tid >> 5;
  const int tcol = (tid & 31) * 4;
#pragma unroll
  for (int c = 0; c < 4; c++) {
    if (wm == (c >> 1)) {
      const int i0 = 2 * (c & 1);
#pragma unroll
      for (int ii = 0; ii < 2; ii++)
#pragma unroll
        for (int j = 0; j < 4; j++)
          *(f32x4*)(lsC + (ii * 16 + mloc) * LDC + wn * 64 + j * 16 + ng) =
              acc[i0 + ii][j];
    }
    __syncthreads();
#pragma unroll
    for (int rr = 0; rr < 4; rr++) {
      const int r = rr * 8 + trow;
      const size_t gr = row0 + c * 32 + r;
      f32x4 v = *(const f32x4*)(lsC + r * LDC + tcol);
      if (!BF16OUT) {
        *(f32x4*)((float*)Cout + gr * N + col0 + tcol) = v;
      } else {
        u16x4 o;
#pragma unroll
        for (int q = 0; q < 4; q++) o[q] = f2bf(v[q]);
        *(u16x4*)((unsigned short*)Cout + gr * N + col0 + tcol) = o;
      }
    }
    __syncthreads();
  }
}

// ---------------------------------------------------------------------------
// FINAL vocab GEMM: 256x256 tile, 8 waves (2x4), wave tile 128x64, BK=64,
// XOR-swizzled LDS, 2-deep double buffer with counted vmcnt(8).
// C[M,N] = A[M,K]*B[N,K]^T + bias, fp32 nt full-line out.
// ROWFAST grid: blockIdx.x = row-block (fastest), blockIdx.y = col-block.
__global__ __launch_bounds__(512) void gemm_final256(
    const unsigned short* __restrict__ A, const unsigned short* __restrict__ B,
    float* __restrict__ C, const float* __restrict__ bias, int M, int N,
    int K) {
  __shared__ __align__(16) char smem[131072];
  float* const lsC = (float*)smem;  // epilogue union

  const int t = threadIdx.x;
  const int l = t & 63;
  const int w = __builtin_amdgcn_readfirstlane(t >> 6);  // 0..7
  const int wm = w >> 2, wn = w & 3;
  const int row0 = blockIdx.x * 256;
  const int col0 = blockIdx.y * 256;

  const int srow = t >> 3;                    // 0..63
  const int sg = ((t & 7) ^ (srow & 7)) * 8;  // pre-swizzled global elem off
  const unsigned short* aS0 = A + (size_t)(row0 + srow) * K + sg;
  const unsigned short* aS1 = A + (size_t)(row0 + 64 + srow) * K + sg;
  const unsigned short* aS2 = A + (size_t)(row0 + 128 + srow) * K + sg;
  const unsigned short* aS3 = A + (size_t)(row0 + 192 + srow) * K + sg;
  int b0 = min(col0 + srow, N - 1);
  int b1 = min(col0 + 64 + srow, N - 1);
  int b2 = min(col0 + 128 + srow, N - 1);
  int b3 = min(col0 + 192 + srow, N - 1);
  const unsigned short* bS0 = B + (size_t)b0 * K + sg;
  const unsigned short* bS1 = B + (size_t)b1 * K + sg;
  const unsigned short* bS2 = B + (size_t)b2 * K + sg;
  const unsigned short* bS3 = B + (size_t)b3 * K + sg;
  const int wOff = w * 1024;

  const int aRowB = (wm * 128 + (l & 15)) * 128;
  const int bRowB = (wn * 64 + (l & 15)) * 128;
  const int gk0 = ((l >> 4) ^ (l & 7)) * 16;
  const int gk1 = ((4 + (l >> 4)) ^ (l & 7)) * 16;

  f32x4 acc[8][4] = {};

#define STAGE(BUF, KOFF)                       \
  do {                                         \
    char* a_ = smem + (BUF) * 65536;           \
    char* b_ = a_ + 32768;                     \
    gload16(aS0 + (KOFF), a_ + wOff);          \
    gload16(aS1 + (KOFF), a_ + 8192 + wOff);   \
    gload16(aS2 + (KOFF), a_ + 16384 + wOff);  \
    gload16(aS3 + (KOFF), a_ + 24576 + wOff);  \
    gload16(bS0 + (KOFF), b_ + wOff);          \
    gload16(bS1 + (KOFF), b_ + 8192 + wOff);   \
    gload16(bS2 + (KOFF), b_ + 16384 + wOff);  \
    gload16(bS3 + (KOFF), b_ + 24576 + wOff);  \
  } while (0)

  STAGE(0, 0);

  const int NK = K >> 6;
  for (int kt = 0; kt < NK; ++kt) {
    const int cur = kt & 1;
    const char* aB = smem + cur * 65536;
    const char* bB = aB + 32768;

    if (kt + 1 < NK) {
      STAGE(cur ^ 1, (kt + 1) << 6);
      asm volatile("s_waitcnt vmcnt(8)" ::: "memory");
    } else {
      asm volatile("s_waitcnt vmcnt(0)" ::: "memory");
    }
    __builtin_amdgcn_s_barrier();
    MEMFENCE;

    bf16x8 bf[4][2];
#pragma unroll
    for (int j = 0; j < 4; j++) {
      bf[j][0] = *(const bf16x8*)(bB + bRowB + j * 2048 + gk0);
      bf[j][1] = *(const bf16x8*)(bB + bRowB + j * 2048 + gk1);
    }
#pragma unroll
    for (int h = 0; h < 2; h++) {
      bf16x8 af[4][2];
#pragma unroll
      for (int i = 0; i < 4; i++) {
        af[i][0] = *(const bf16x8*)(aB + aRowB + (h * 4 + i) * 2048 + gk0);
        af[i][1] = *(const bf16x8*)(aB + aRowB + (h * 4 + i) * 2048 + gk1);
      }
#pragma unroll
      for (int i = 0; i < 4; i++)
#pragma unroll
        for (int j = 0; j < 4; j++) {
          acc[h * 4 + i][j] = __builtin_amdgcn_mfma_f32_16x16x32_bf16(
              bf[j][0], af[i][0], acc[h * 4 + i][j], 0, 0, 0);
          acc[h * 4 + i][j] = __builtin_amdgcn_mfma_f32_16x16x32_bf16(
              bf[j][1], af[i][1], acc[h * 4 + i][j], 0, 0, 0);
        }
    }

    MEMFENCE;
    __builtin_amdgcn_s_barrier();
    MEMFENCE;
  }
#undef STAGE

  // ---- Epilogue: LDS transpose -> full-line nt streaming stores ----
  // LDC=260: 260%32=4 -> 2-way bank aliasing (free, m136). 1040B rows,
  // 16B-aligned (1040 = 65*16).
  const int mloc = l & 15;
  const int ng = (l >> 4) * 4;
  const int LDC = 260;
#pragma unroll
  for (int c = 0; c < 8; c++) {
    if (wm == (c >> 2)) {
      const int fr0 = (c & 3) * 2;
#pragma unroll
      for (int ii = 0; ii < 2; ii++)
#pragma unroll
        for (int j = 0; j < 4; j++)
          *(f32x4*)(lsC + (ii * 16 + mloc) * LDC + wn * 64 + j * 16 + ng) =
              acc[fr0 + ii][j];
    }
    __syncthreads();
#pragma unroll
    for (int rr = 0; rr < 4; rr++) {
      const int r = rr * 8 + (t >> 6);
      const size_t gr = row0 + c * 32 + r;
      f32x4 v = *(const f32x4*)(lsC + r * LDC + (t & 63) * 4);
      const int n0 = col0 + (t & 63) * 4;
      if (col0 + 256 <= N) {
        const f32x4u bv = *(const f32x4u*)(bias + n0);
        f32x4u o;
#pragma unroll
        for (int q = 0; q < 4; q++) o[q] = v[q] + bv[q];
        __builtin_nontemporal_store(o, (f32x4u*)(C + gr * N + n0));
      } else {
#pragma unroll
        for (int q = 0; q < 4; q++)
          if (n0 + q < N) C[gr * N + n0 + q] = v[q] + bias[n0 + q];
      }
    }
    __syncthreads();
  }
}

// ---------------------------------------------------------------------------
// MinGRU scan, 3-kernel chunked linear recurrence. gh/res in BF16, state fp32.
__device__ __forceinline__ void gru_step(float gate, float hid, float& a,
                                         float& g) {
  a = 1.f / (1.f + expf(gate));  // sigmoid(-gate)
  g = (hid >= 0.f) ? (hid + 0.5f) : 1.f / (1.f + expf(-hid));
}

__global__ __launch_bounds__(256) void scan_compose(
    const unsigned short* __restrict__ gh, float* __restrict__ Acl,
    float* __restrict__ Vcl) {
  int ck = blockIdx.x;
  int hp = blockIdx.y * 256 + threadIdx.x;
  int b = hp >> 10, h = hp & 1023;
  const unsigned short* gb = gh + ((size_t)(b * 2048 + ck * 64)) * 2048 + h;
  float A = 1.f, V = 0.f;
  for (int t = 0; t < 64; t++) {
    float gate = bf2f(gb[(size_t)t * 2048]);
    float hid = bf2f(gb[(size_t)t * 2048 + 1024]);
    float a, g;
    gru_step(gate, hid, a, g);
    V = a * V + (1.f - a) * g;
    A *= a;
  }
  size_t i = (size_t)(b * 32 + ck) * 1024 + h;
  Acl[i] = A;
  Vcl[i] = V;
}

__global__ __launch_bounds__(256) void scan_prefix(
    const float* __restrict__ Acl, const float* __restrict__ Vcl,
    float* __restrict__ Hin) {
  int hp = blockIdx.x * 256 + threadIdx.x;
  int b = hp >> 10, h = hp & 1023;
  float hr = 0.5f;
  for (int ck = 0; ck < 32; ck++) {
    size_t i = (size_t)(b * 32 + ck) * 1024 + h;
    Hin[i] = hr;
    hr = Acl[i] * hr + Vcl[i];
  }
}

// RESBF=1: residual buffer is bf16 (layer 0's r0); else fp32. Output fp32.
template <int RESBF>
__global__ __launch_bounds__(256) void scan_emit(
    const unsigned short* __restrict__ gh, const float* __restrict__ Hin,
    const void* __restrict__ res, float* __restrict__ xout) {
  int ck = blockIdx.x;
  int hp = blockIdx.y * 256 + threadIdx.x;
  int b = hp >> 10, h = hp & 1023;
  const unsigned short* gb = gh + ((size_t)(b * 2048 + ck * 64)) * 2048 + h;
  const size_t rbase = ((size_t)(b * 2048 + ck * 64)) * 1024 + h;
  const unsigned short* rb16 = (const unsigned short*)res + rbase;
  const float* rb32 = (const float*)res + rbase;
  float* ob = xout + rbase;
  float hc = Hin[(size_t)(b * 32 + ck) * 1024 + h];
  for (int t = 0; t < 64; t++) {
    float gate = bf2f(gb[(size_t)t * 2048]);
    float hid = bf2f(gb[(size_t)t * 2048 + 1024]);
    float a, g;
    gru_step(gate, hid, a, g);
    hc = a * hc + (1.f - a) * g;
    float r = RESBF ? bf2f(rb16[(size_t)t * 1024]) : rb32[(size_t)t * 1024];
    ob[(size_t)t * 1024] = hc + r;
  }
}

// ---------------------------------------------------------------------------
extern "C" void kernel_launch(void* const* d_in, const int* in_sizes, int n_in,
                              void* d_out, int out_size, void* d_ws,
                              size_t ws_size, hipStream_t stream) {
  (void)in_sizes; (void)n_in; (void)out_size; (void)ws_size;
  const int* ids = (const int*)d_in[0];
  const float* embW = (const float*)d_in[1];
  const float* ln0w = (const float*)d_in[2];
  const float* ln0b = (const float*)d_in[3];
  const float* g0W = (const float*)d_in[4];
  const float* ln1w = (const float*)d_in[5];
  const float* ln1b = (const float*)d_in[6];
  const float* g1W = (const float*)d_in[7];
  const float* ln2w = (const float*)d_in[8];
  const float* ln2b = (const float*)d_in[9];
  const float* g2W = (const float*)d_in[10];
  const float* r0W = (const float*)d_in[11];
  const float* lnfw = (const float*)d_in[12];
  const float* lnfb = (const float*)d_in[13];
  const float* fcW = (const float*)d_in[14];
  const float* fcb = (const float*)d_in[15];
  float* out = (float*)d_out;

  const int M = 4096;  // B*S
  const int V = 50257;

  // Workspace layout (~158 MB total).
  char* ws = (char*)d_ws;
  unsigned short* x_bf = (unsigned short*)(ws + 0);           //  6,291,456
  float* x_f = (float*)(ws + 6291456);                        // 16,777,216
  unsigned short* xn_bf = (unsigned short*)(ws + 23068672);   //  8,388,608
  unsigned short* gh_bf = (unsigned short*)(ws + 31457280);   // 16,777,216
  unsigned short* r0_bf = (unsigned short*)(ws + 48234496);   //  8,388,608
  float* Acl = (float*)(ws + 56623104);                       //    262,144
  float* Vcl = (float*)(ws + 56885248);                       //    262,144
  float* Hin = (float*)(ws + 57147392);                       //    262,144
  unsigned short* gwbf = (unsigned short*)(ws + 57409536);    //  4,194,304
  unsigned short* rwbf = (unsigned short*)(ws + 61603840);    //  1,572,864
  unsigned short* fcwbf = (unsigned short*)(ws + 63176704);   // 102,926,336

  auto cvt = [&](const float* src, unsigned short* dst, int n) {
    int n8 = n / 8;
    int grid = min((n8 + 255) / 256, 2048);
    cvt_kernel<<<grid, 256, 0, stream>>>(src, dst, n8);
  };

  embed_kernel<<<M, 256, 0, stream>>>(ids, embW, x_bf);
  cvt(fcW, fcwbf, V * 1024);
  cvt(r0W, rwbf, 1024 * 768);

  // ---- layer 0 (in 768 -> out 1024, residual = x @ res0_W^T) ----
  cvt(g0W, gwbf, 2048 * 768);
  ln_kernel<1, 768><<<M, 256, 0, stream>>>(x_bf, ln0w, ln0b, xn_bf, 1e-5f);
  gemm_bt<1><<<dim3(16, 32), 256, 0, stream>>>(xn_bf, gwbf, gh_bf, M, 2048,
                                               768);
  gemm_bt<1><<<dim3(8, 32), 256, 0, stream>>>(x_bf, rwbf, r0_bf, M, 1024, 768);
  scan_compose<<<dim3(32, 8), 256, 0, stream>>>(gh_bf, Acl, Vcl);
  scan_prefix<<<8, 256, 0, stream>>>(Acl, Vcl, Hin);
  scan_emit<1><<<dim3(32, 8), 256, 0, stream>>>(gh_bf, Hin, r0_bf, x_f);

  // ---- layer 1 (identity residual) ----
  cvt(g1W, gwbf, 2048 * 1024);
  ln_kernel<0, 1024><<<M, 256, 0, stream>>>(x_f, ln1w, ln1b, xn_bf, 1e-5f);
  gemm_bt<1><<<dim3(16, 32), 256, 0, stream>>>(xn_bf, gwbf, gh_bf, M, 2048,
                                               1024);
  scan_compose<<<dim3(32, 8), 256, 0, stream>>>(gh_bf, Acl, Vcl);
  scan_prefix<<<8, 256, 0, stream>>>(Acl, Vcl, Hin);
  scan_emit<0><<<dim3(32, 8), 256, 0, stream>>>(gh_bf, Hin, x_f, x_f);

  // ---- layer 2 (identity residual) ----
  cvt(g2W, gwbf, 2048 * 1024);
  ln_kernel<0, 1024><<<M, 256, 0, stream>>>(x_f, ln2w, ln2b, xn_bf, 1e-5f);
  gemm_bt<1><<<dim3(16, 32), 256, 0, stream>>>(xn_bf, gwbf, gh_bf, M, 2048,
                                               1024);
  scan_compose<<<dim3(32, 8), 256, 0, stream>>>(gh_bf, Acl, Vcl);
  scan_prefix<<<8, 256, 0, stream>>>(Acl, Vcl, Hin);
  scan_emit<0><<<dim3(32, 8), 256, 0, stream>>>(gh_bf, Hin, x_f, x_f);

  // ---- final LN (eps=0) + vocab GEMM (256^2, dbuf+vmcnt(8)), fp32 out ----
  ln_kernel<0, 1024><<<M, 256, 0, stream>>>(x_f, lnfw, lnfb, xn_bf, 0.0f);
  gemm_final256<<<dim3(16, (V + 255) / 256), 512, 0, stream>>>(
      xn_bf, fcwbf, out, fcb, M, V, 1024);
}